// Round 1
// baseline (371.388 us; speedup 1.0000x reference)
//
#include <hip/hip_runtime.h>
#include <hip/hip_bf16.h>

// Problem: B=1024, N=32, D=512, H=4, HD=128
// out = OutProj( Attention( QKVProj(x) ) )
//
// Stage 1: qkv = X(32768x512) @ Win^T(512x1536) + bin   -> bf16 in ws
// Stage 2: per (b,h): S = Q K^T / sqrt(128), mask diag+pad, softmax, ctx = P V -> f32 in ws
// Stage 3: out = ctx(32768x512) @ Wout^T(512x512) + bout -> f32 d_out

typedef __attribute__((ext_vector_type(4))) float  f32x4;
typedef __attribute__((ext_vector_type(8))) short  bf16x8;
typedef __attribute__((ext_vector_type(4))) short  bf16x4;
typedef __attribute__((ext_vector_type(4))) int    i32x4;

__device__ __forceinline__ unsigned short f2bf(float f) {
    unsigned u = __builtin_bit_cast(unsigned, f);
    u = (u + 0x7FFFu + ((u >> 16) & 1u)) >> 16;   // RNE
    return (unsigned short)u;
}
__device__ __forceinline__ float bf2f(unsigned short h) {
    unsigned u = ((unsigned)h) << 16;
    return __builtin_bit_cast(float, u);
}

// ---------------------------------------------------------------------------
// BT-layout bf16 MFMA GEMM: C[M x N] = A[M x K(=512)] * Bw[N x K]^T + bias[N]
// Block tile 128x128, BK=64, 256 threads (4 waves, 2x2), 16x16x32 MFMA.
// A, Bw are f32 in global; converted to bf16 during LDS staging.
// LDS rows are 64 bf16 (128B); 16B chunks XOR-swizzled by (row&7) so the
// fragment ds_read_b128 (16 lanes, stride 128B) is 2-way max (free, m136).
// MODE 0: store bf16 (qkv buffer).  MODE 1: store f32 (d_out).
// ---------------------------------------------------------------------------
template<int MODE>
__global__ __launch_bounds__(256)
void gemm_bt(const float* __restrict__ A, const float* __restrict__ Bw,
             const float* __restrict__ bias, void* __restrict__ Cout, int ldc)
{
    __shared__ unsigned short As[128 * 64];
    __shared__ unsigned short Bs[128 * 64];

    const int t = threadIdx.x;
    const int mbase = blockIdx.y * 128;
    const int nbase = blockIdx.x * 128;
    const int w = t >> 6, l = t & 63;
    const int wr = w >> 1, wc = w & 1;
    const int lg = l >> 4, lr = l & 15;

    f32x4 acc[4][4] = {};

    for (int ks = 0; ks < 512; ks += 64) {
        __syncthreads();   // previous compute must finish before LDS overwrite
        // ---- stage A and B tiles (f32 -> bf16, swizzled) ----
#pragma unroll
        for (int i = 0; i < 8; ++i) {
            int f  = t + i * 256;          // float4 id within 128x16 f4-tile
            int r  = f >> 4;               // row 0..127
            int c4 = f & 15;               // float4 within row (k = c4*4..+3)
            f32x4 av = *(const f32x4*)(A  + (size_t)(mbase + r) * 512 + ks + c4 * 4);
            f32x4 bv = *(const f32x4*)(Bw + (size_t)(nbase + r) * 512 + ks + c4 * 4);
            int ch  = c4 >> 1;                                   // 16B chunk 0..7
            int idx = r * 64 + ((ch ^ (r & 7)) << 3) + (c4 & 1) * 4;
            bf16x4 ap, bp;
#pragma unroll
            for (int e = 0; e < 4; ++e) { ap[e] = (short)f2bf(av[e]); bp[e] = (short)f2bf(bv[e]); }
            *(bf16x4*)&As[idx] = ap;
            *(bf16x4*)&Bs[idx] = bp;
        }
        __syncthreads();
        // ---- compute: 2 k-slices of 32, 4x4 fragments per wave ----
#pragma unroll
        for (int kk = 0; kk < 64; kk += 32) {
            int kc8 = (kk >> 3) + lg;      // 16B chunk holding this lane's 8 k's
            bf16x8 af[4], bfr[4];
#pragma unroll
            for (int mi = 0; mi < 4; ++mi) {
                int r = wr * 64 + mi * 16 + lr;
                af[mi] = *(const bf16x8*)&As[r * 64 + ((kc8 ^ (r & 7)) << 3)];
            }
#pragma unroll
            for (int ni = 0; ni < 4; ++ni) {
                int n = wc * 64 + ni * 16 + lr;
                bfr[ni] = *(const bf16x8*)&Bs[n * 64 + ((kc8 ^ (n & 7)) << 3)];
            }
#pragma unroll
            for (int mi = 0; mi < 4; ++mi)
#pragma unroll
                for (int ni = 0; ni < 4; ++ni)
                    acc[mi][ni] = __builtin_amdgcn_mfma_f32_16x16x32_bf16(
                        af[mi], bfr[ni], acc[mi][ni], 0, 0, 0);
        }
    }

    // ---- epilogue: C/D layout col=lane&15, row=(lane>>4)*4+reg ----
#pragma unroll
    for (int ni = 0; ni < 4; ++ni) {
        int col = nbase + wc * 64 + ni * 16 + lr;
        float bv = bias[col];
#pragma unroll
        for (int mi = 0; mi < 4; ++mi) {
            int row0 = mbase + wr * 64 + mi * 16 + lg * 4;
#pragma unroll
            for (int ri = 0; ri < 4; ++ri) {
                float v = acc[mi][ni][ri] + bv;
                if (MODE == 0)
                    ((unsigned short*)Cout)[(size_t)(row0 + ri) * ldc + col] = f2bf(v);
                else
                    ((float*)Cout)[(size_t)(row0 + ri) * ldc + col] = v;
            }
        }
    }
}

// ---------------------------------------------------------------------------
// Attention: one block per (b,h). qkv bf16 in, ctx f32 out.
// LDS: Q/K/V staged as f32, rows of 32 float4-chunks, chunk XOR-swizzled by
// row so both the score loop (lanes read 8 different k-rows at same d4) and
// the PV loop (lanes read 8 different d4-chunks at same k-row) are
// conflict-free. Softmax: 8 lanes own one q-row (4 cols each), __shfl_xor.
// ---------------------------------------------------------------------------
__global__ __launch_bounds__(256)
void attn_kernel(const unsigned short* __restrict__ qkv,
                 const unsigned char* __restrict__ pad,
                 float* __restrict__ ctx)
{
    __shared__ f32x4 Qs[32 * 32];
    __shared__ f32x4 Ks[32 * 32];
    __shared__ f32x4 Vs[32 * 32];
    __shared__ float Ps[32 * 33];

    const int bid = blockIdx.x;
    const int b = bid >> 2, h = bid & 3;
    const int t = threadIdx.x;
    const int r = t >> 3, j = t & 7;     // staging: row r, 16-elem slice j

    // ---- stage Q,K,V (bf16 -> f32, swizzled chunks) ----
    const unsigned short* base = qkv + ((size_t)(b * 32 + r) * 1536 + h * 128);
#pragma unroll
    for (int sel = 0; sel < 3; ++sel) {
        f32x4* dst = (sel == 0) ? Qs : (sel == 1) ? Ks : Vs;
        const unsigned short* src = base + sel * 512 + j * 16;
#pragma unroll
        for (int it = 0; it < 2; ++it) {
            i32x4 raw = *(const i32x4*)(src + it * 8);
            float fv[8];
#pragma unroll
            for (int e = 0; e < 8; ++e) {
                unsigned word = ((const unsigned*)&raw)[e >> 1];
                unsigned short hb = (e & 1) ? (unsigned short)(word >> 16)
                                            : (unsigned short)(word & 0xffffu);
                fv[e] = bf2f(hb);
            }
            int c0 = j * 4 + it * 2;
            f32x4 v0 = {fv[0], fv[1], fv[2], fv[3]};
            f32x4 v1 = {fv[4], fv[5], fv[6], fv[7]};
            dst[r * 32 + ((c0    ) ^ r)] = v0;
            dst[r * 32 + ((c0 + 1) ^ r)] = v1;
        }
    }
    __syncthreads();

    // ---- scores: thread (q = r, cols kc..kc+3), dot over 128 ----
    const int q  = r;
    const int kc = j * 4;
    float s[4] = {0.f, 0.f, 0.f, 0.f};
#pragma unroll 4
    for (int d4 = 0; d4 < 32; ++d4) {
        f32x4 qv = Qs[q * 32 + (d4 ^ q)];
#pragma unroll
        for (int jj = 0; jj < 4; ++jj) {
            f32x4 kv = Ks[(kc + jj) * 32 + (d4 ^ (kc + jj))];
#pragma unroll
            for (int e = 0; e < 4; ++e) s[jj] = fmaf(qv[e], kv[e], s[jj]);
        }
    }
    const float sc = 0.08838834764831845f;   // 1/sqrt(128)
    float m = -INFINITY;
#pragma unroll
    for (int jj = 0; jj < 4; ++jj) {
        int kcol = kc + jj;
        bool msk = (kcol == q) || (pad[b * 32 + kcol] != 0);
        s[jj] = msk ? -INFINITY : s[jj] * sc;
        m = fmaxf(m, s[jj]);
    }
    m = fmaxf(m, __shfl_xor(m, 1));
    m = fmaxf(m, __shfl_xor(m, 2));
    m = fmaxf(m, __shfl_xor(m, 4));
    float p[4], sum = 0.f;
#pragma unroll
    for (int jj = 0; jj < 4; ++jj) { p[jj] = __expf(s[jj] - m); sum += p[jj]; }
    sum += __shfl_xor(sum, 1);
    sum += __shfl_xor(sum, 2);
    sum += __shfl_xor(sum, 4);
#pragma unroll
    for (int jj = 0; jj < 4; ++jj) Ps[q * 33 + kc + jj] = p[jj];
    __syncthreads();

    // ---- PV: thread (q, d-chunks {j, j+8, j+16, j+24}) ----
    float c[16] = {0.f};
#pragma unroll 4
    for (int k = 0; k < 32; ++k) {
        float pv = Ps[q * 33 + k];
#pragma unroll
        for (int cc = 0; cc < 4; ++cc) {
            f32x4 vv = Vs[k * 32 + ((j + 8 * cc) ^ k)];
#pragma unroll
            for (int e = 0; e < 4; ++e) c[cc * 4 + e] = fmaf(pv, vv[e], c[cc * 4 + e]);
        }
    }
    const float inv = 1.0f / sum;
    float* co = ctx + (size_t)(b * 32 + q) * 512 + h * 128;
#pragma unroll
    for (int cc = 0; cc < 4; ++cc) {
        f32x4 ov = {c[cc * 4 + 0] * inv, c[cc * 4 + 1] * inv,
                    c[cc * 4 + 2] * inv, c[cc * 4 + 3] * inv};
        *(f32x4*)(co + (j + 8 * cc) * 4) = ov;
    }
}

// ---------------------------------------------------------------------------
extern "C" void kernel_launch(void* const* d_in, const int* in_sizes, int n_in,
                              void* d_out, int out_size, void* d_ws, size_t ws_size,
                              hipStream_t stream)
{
    const float*         X    = (const float*)d_in[0];
    const unsigned char* pad  = (const unsigned char*)d_in[1];  // all-false in bench
    const float*         Win  = (const float*)d_in[2];          // (1536, 512)
    const float*         bin  = (const float*)d_in[3];          // (1536,)
    const float*         Wout = (const float*)d_in[4];          // (512, 512)
    const float*         bout = (const float*)d_in[5];          // (512,)
    float*               out  = (float*)d_out;                  // (1024,32,512) f32

    unsigned short* qkvb = (unsigned short*)d_ws;                         // 96 MiB bf16
    float*          ctxb = (float*)((char*)d_ws + (size_t)100663296);     // 64 MiB f32

    dim3 blk(256);
    // qkv projection: M=32768 (256 tiles), N=1536 (12 tiles)
    gemm_bt<0><<<dim3(12, 256), blk, 0, stream>>>(X, Win, bin, qkvb, 1536);
    // attention: 1024 batches x 4 heads
    attn_kernel<<<dim3(4096), blk, 0, stream>>>(qkvb, pad, ctxb);
    // output projection: N=512 (4 tiles)
    gemm_bt<1><<<dim3(4, 256), blk, 0, stream>>>(ctxb, Wout, bout, out, 512);
}

// Round 2
// 313.524 us; speedup vs baseline: 1.1846x; 1.1846x over previous
//
#include <hip/hip_runtime.h>
#include <hip/hip_bf16.h>

// Problem: B=1024, N=32, D=512, H=4, HD=128
// Pipeline:
//   cvt:   X, Win, Wout f32 -> bf16 (one elementwise pass)
//   qkv  = Xb(32768x512) @ Winb^T + bin          -> bf16 qkvb   (m97 MFMA GEMM)
//   attn: per (b,h) 32x32 masked softmax-attn    -> bf16 ctxb
//   out  = ctxb @ Woutb^T + bout                 -> f32 d_out   (m97 MFMA GEMM)

typedef __attribute__((ext_vector_type(4))) float  f32x4;
typedef __attribute__((ext_vector_type(8))) short  bf16x8;
typedef __attribute__((ext_vector_type(4))) short  bf16x4;
typedef __attribute__((ext_vector_type(4))) int    i32x4;

__device__ __forceinline__ unsigned short f2bf(float f) {
    unsigned u = __builtin_bit_cast(unsigned, f);
    u = (u + 0x7FFFu + ((u >> 16) & 1u)) >> 16;   // RNE
    return (unsigned short)u;
}
__device__ __forceinline__ float bf2f(unsigned short h) {
    unsigned u = ((unsigned)h) << 16;
    return __builtin_bit_cast(float, u);
}

__device__ __forceinline__ void gload_lds16(const void* g, void* l) {
    __builtin_amdgcn_global_load_lds(
        (const __attribute__((address_space(1))) void*)g,
        (__attribute__((address_space(3))) void*)l, 16, 0, 0);
}

// ---------------------------------------------------------------------------
// f32 -> bf16 elementwise (float4 / bf16x4 vectorized)
// ---------------------------------------------------------------------------
__global__ __launch_bounds__(256)
void cvt_kernel(const float* __restrict__ src, unsigned short* __restrict__ dst, int n4)
{
    int i = blockIdx.x * 256 + threadIdx.x;
    if (i >= n4) return;
    f32x4 v = ((const f32x4*)src)[i];
    bf16x4 o;
#pragma unroll
    for (int e = 0; e < 4; ++e) o[e] = (short)f2bf(v[e]);
    ((bf16x4*)dst)[i] = o;
}

// ---------------------------------------------------------------------------
// m97-structure bf16 MFMA GEMM (BT layout): C[MxN] = A[MxK=512] * Bw[NxK]^T + bias
// 128x128 tile, BK=64, 256 threads (4 waves, 2x2), 16x16x32 MFMA.
// Staging via global_load_lds width=16 into LINEAR LDS (wave-uniform base +
// lane*16 — guide m104). XCD-aware bijective block swizzle (nwg % 8 == 0).
// MODE 0: bf16 store.  MODE 1: f32 store.
// ---------------------------------------------------------------------------
template<int MODE>
__global__ __launch_bounds__(256)
void gemm_bt(const unsigned short* __restrict__ A, const unsigned short* __restrict__ Bw,
             const float* __restrict__ bias, void* __restrict__ Cout, int ldc, int ntx)
{
    __shared__ unsigned short As[128 * 64];
    __shared__ unsigned short Bs[128 * 64];

    const int t = threadIdx.x;
    // XCD swizzle: nwg is a multiple of 8 for both call sites
    const int nwg = gridDim.x;
    const int cpx = nwg >> 3;
    const int lin = blockIdx.x;
    const int swz = (lin & 7) * cpx + (lin >> 3);
    const int bx = swz % ntx, by = swz / ntx;
    const int mbase = by * 128, nbase = bx * 128;

    const int w = t >> 6, l = t & 63;
    const int wr = w >> 1, wc = w & 1;
    const int lg = l >> 4, lr = l & 15;

    f32x4 acc[4][4] = {};

    for (int ks = 0; ks < 512; ks += 64) {
        __syncthreads();   // previous tile's compute done before overwrite
        // ---- stage A and B tiles: 1024 16B-chunks each, 4 per thread ----
#pragma unroll
        for (int i = 0; i < 4; ++i) {
            int c   = i * 256 + t;          // chunk id: row = c>>3, k-slice = c&7
            int row = c >> 3;
            int ke  = (c & 7) * 8;          // k element offset within BK
            // wave-uniform LDS base: chunk (i*256 + w*64), hw adds lane*16
            gload_lds16(A  + (size_t)(mbase + row) * 512 + ks + ke,
                        &As[(size_t)(i * 256 + w * 64) * 8]);
            gload_lds16(Bw + (size_t)(nbase + row) * 512 + ks + ke,
                        &Bs[(size_t)(i * 256 + w * 64) * 8]);
        }
        __syncthreads();   // compiler emits vmcnt(0) drain here
        // ---- compute: 2 k-slices of 32, 4x4 fragments per wave ----
#pragma unroll
        for (int kk = 0; kk < 64; kk += 32) {
            bf16x8 af[4], bfr[4];
#pragma unroll
            for (int mi = 0; mi < 4; ++mi)
                af[mi] = *(const bf16x8*)&As[(wr * 64 + mi * 16 + lr) * 64 + kk + lg * 8];
#pragma unroll
            for (int ni = 0; ni < 4; ++ni)
                bfr[ni] = *(const bf16x8*)&Bs[(wc * 64 + ni * 16 + lr) * 64 + kk + lg * 8];
#pragma unroll
            for (int mi = 0; mi < 4; ++mi)
#pragma unroll
                for (int ni = 0; ni < 4; ++ni)
                    acc[mi][ni] = __builtin_amdgcn_mfma_f32_16x16x32_bf16(
                        af[mi], bfr[ni], acc[mi][ni], 0, 0, 0);
        }
    }

    // ---- epilogue: C/D layout col=lane&15, row=(lane>>4)*4+reg ----
#pragma unroll
    for (int ni = 0; ni < 4; ++ni) {
        int col = nbase + wc * 64 + ni * 16 + lr;
        float bv = bias[col];
#pragma unroll
        for (int mi = 0; mi < 4; ++mi) {
            int row0 = mbase + wr * 64 + mi * 16 + lg * 4;
#pragma unroll
            for (int ri = 0; ri < 4; ++ri) {
                float v = acc[mi][ni][ri] + bv;
                if (MODE == 0)
                    ((unsigned short*)Cout)[(size_t)(row0 + ri) * ldc + col] = f2bf(v);
                else
                    ((float*)Cout)[(size_t)(row0 + ri) * ldc + col] = v;
            }
        }
    }
}

// ---------------------------------------------------------------------------
// Attention: one block per (b,h). qkv bf16 in, ctx bf16 out.
// f32 LDS tiles with chunk-XOR swizzle (conflict-free on both access axes).
// Softmax: 8 lanes own one q-row (4 cols each), __shfl_xor reduce.
// ---------------------------------------------------------------------------
__global__ __launch_bounds__(256)
void attn_kernel(const unsigned short* __restrict__ qkv,
                 const unsigned char* __restrict__ pad,
                 unsigned short* __restrict__ ctx)
{
    __shared__ f32x4 Qs[32 * 32];
    __shared__ f32x4 Ks[32 * 32];
    __shared__ f32x4 Vs[32 * 32];
    __shared__ float Ps[32 * 33];

    const int bid = blockIdx.x;
    const int b = bid >> 2, h = bid & 3;
    const int t = threadIdx.x;
    const int r = t >> 3, j = t & 7;     // staging: row r, 16-elem slice j

    // ---- stage Q,K,V (bf16 -> f32, swizzled chunks) ----
    const unsigned short* base = qkv + ((size_t)(b * 32 + r) * 1536 + h * 128);
#pragma unroll
    for (int sel = 0; sel < 3; ++sel) {
        f32x4* dst = (sel == 0) ? Qs : (sel == 1) ? Ks : Vs;
        const unsigned short* src = base + sel * 512 + j * 16;
#pragma unroll
        for (int it = 0; it < 2; ++it) {
            i32x4 raw = *(const i32x4*)(src + it * 8);
            float fv[8];
#pragma unroll
            for (int e = 0; e < 8; ++e) {
                unsigned word = ((const unsigned*)&raw)[e >> 1];
                unsigned short hb = (e & 1) ? (unsigned short)(word >> 16)
                                            : (unsigned short)(word & 0xffffu);
                fv[e] = bf2f(hb);
            }
            int c0 = j * 4 + it * 2;
            f32x4 v0 = {fv[0], fv[1], fv[2], fv[3]};
            f32x4 v1 = {fv[4], fv[5], fv[6], fv[7]};
            dst[r * 32 + ((c0    ) ^ r)] = v0;
            dst[r * 32 + ((c0 + 1) ^ r)] = v1;
        }
    }
    __syncthreads();

    // ---- scores: thread (q = r, cols kc..kc+3), dot over 128 ----
    const int q  = r;
    const int kc = j * 4;
    float s[4] = {0.f, 0.f, 0.f, 0.f};
#pragma unroll 4
    for (int d4 = 0; d4 < 32; ++d4) {
        f32x4 qv = Qs[q * 32 + (d4 ^ q)];
#pragma unroll
        for (int jj = 0; jj < 4; ++jj) {
            f32x4 kv = Ks[(kc + jj) * 32 + (d4 ^ (kc + jj))];
#pragma unroll
            for (int e = 0; e < 4; ++e) s[jj] = fmaf(qv[e], kv[e], s[jj]);
        }
    }
    const float sc = 0.08838834764831845f;   // 1/sqrt(128)
    float m = -INFINITY;
#pragma unroll
    for (int jj = 0; jj < 4; ++jj) {
        int kcol = kc + jj;
        bool msk = (kcol == q) || (pad[b * 32 + kcol] != 0);
        s[jj] = msk ? -INFINITY : s[jj] * sc;
        m = fmaxf(m, s[jj]);
    }
    m = fmaxf(m, __shfl_xor(m, 1));
    m = fmaxf(m, __shfl_xor(m, 2));
    m = fmaxf(m, __shfl_xor(m, 4));
    float p[4], sum = 0.f;
#pragma unroll
    for (int jj = 0; jj < 4; ++jj) { p[jj] = __expf(s[jj] - m); sum += p[jj]; }
    sum += __shfl_xor(sum, 1);
    sum += __shfl_xor(sum, 2);
    sum += __shfl_xor(sum, 4);
#pragma unroll
    for (int jj = 0; jj < 4; ++jj) Ps[q * 33 + kc + jj] = p[jj];
    __syncthreads();

    // ---- PV: thread (q, d-chunks {j, j+8, j+16, j+24}) ----
    float c[16] = {0.f};
#pragma unroll 4
    for (int k = 0; k < 32; ++k) {
        float pv = Ps[q * 33 + k];
#pragma unroll
        for (int cc = 0; cc < 4; ++cc) {
            f32x4 vv = Vs[k * 32 + ((j + 8 * cc) ^ k)];
#pragma unroll
            for (int e = 0; e < 4; ++e) c[cc * 4 + e] = fmaf(pv, vv[e], c[cc * 4 + e]);
        }
    }
    const float inv = 1.0f / sum;
    unsigned short* co = ctx + (size_t)(b * 32 + q) * 512 + h * 128;
#pragma unroll
    for (int cc = 0; cc < 4; ++cc) {
        bf16x4 ov;
#pragma unroll
        for (int e = 0; e < 4; ++e) ov[e] = (short)f2bf(c[cc * 4 + e] * inv);
        *(bf16x4*)(co + (j + 8 * cc) * 4) = ov;
    }
}

// ---------------------------------------------------------------------------
extern "C" void kernel_launch(void* const* d_in, const int* in_sizes, int n_in,
                              void* d_out, int out_size, void* d_ws, size_t ws_size,
                              hipStream_t stream)
{
    const float*         X    = (const float*)d_in[0];
    const unsigned char* pad  = (const unsigned char*)d_in[1];
    const float*         Win  = (const float*)d_in[2];          // (1536, 512)
    const float*         bin  = (const float*)d_in[3];          // (1536,)
    const float*         Wout = (const float*)d_in[4];          // (512, 512)
    const float*         bout = (const float*)d_in[5];          // (512,)
    float*               out  = (float*)d_out;                  // (1024,32,512) f32

    // workspace plan (130.1 MiB total):
    //   [0, 96MiB)        qkvb  bf16 32768x1536
    //   [96MiB, 128MiB)   Xb    bf16 32768x512   -- dead after qkv GEMM,
    //                     ctxb  bf16 32768x512   -- aliases Xb
    //   [128MiB, +1.5MiB) Winb  bf16 1536x512
    //   then              Woutb bf16 512x512
    char* ws = (char*)d_ws;
    unsigned short* qkvb  = (unsigned short*)(ws);
    unsigned short* Xb    = (unsigned short*)(ws + (size_t)100663296);
    unsigned short* ctxb  = Xb;
    unsigned short* Winb  = (unsigned short*)(ws + (size_t)134217728);
    unsigned short* Woutb = (unsigned short*)(ws + (size_t)135790592);

    dim3 blk(256);
    // f32 -> bf16 conversions
    cvt_kernel<<<dim3(16384), blk, 0, stream>>>(X,    Xb,    4194304);
    cvt_kernel<<<dim3(768),   blk, 0, stream>>>(Win,  Winb,  196608);
    cvt_kernel<<<dim3(256),   blk, 0, stream>>>(Wout, Woutb, 65536);
    // qkv projection: 256 M-tiles x 12 N-tiles = 3072 blocks
    gemm_bt<0><<<dim3(3072), blk, 0, stream>>>(Xb, Winb, bin, qkvb, 1536, 12);
    // attention: 1024 batches x 4 heads
    attn_kernel<<<dim3(4096), blk, 0, stream>>>(qkvb, pad, ctxb);
    // output projection: 256 M-tiles x 4 N-tiles = 1024 blocks
    gemm_bt<1><<<dim3(1024), blk, 0, stream>>>(ctxb, Woutb, bout, out, 512, 4);
}

// Round 3
// 288.959 us; speedup vs baseline: 1.2853x; 1.0850x over previous
//
#include <hip/hip_runtime.h>
#include <hip/hip_bf16.h>

// Problem: B=1024, N=32, D=512, H=4, HD=128
// Pipeline:
//   cvt3:  X, Win, Wout f32 -> bf16 (single launch)
//   qkv  = Xb(32768x512) @ Winb^T + bin          -> bf16 qkvb   (dbuf MFMA GEMM)
//   attn: per (b,h) 32x32 masked softmax-attn    -> bf16 ctxb
//   out  = ctxb @ Woutb^T + bout                 -> f32 d_out   (dbuf MFMA GEMM)

typedef __attribute__((ext_vector_type(4))) float  f32x4;
typedef __attribute__((ext_vector_type(8))) short  bf16x8;
typedef __attribute__((ext_vector_type(4))) short  bf16x4;
typedef __attribute__((ext_vector_type(4))) int    i32x4;

__device__ __forceinline__ unsigned short f2bf(float f) {
    unsigned u = __builtin_bit_cast(unsigned, f);
    u = (u + 0x7FFFu + ((u >> 16) & 1u)) >> 16;   // RNE
    return (unsigned short)u;
}
__device__ __forceinline__ float bf2f(unsigned short h) {
    unsigned u = ((unsigned)h) << 16;
    return __builtin_bit_cast(float, u);
}

__device__ __forceinline__ void gload_lds16(const void* g, void* l) {
    __builtin_amdgcn_global_load_lds(
        (const __attribute__((address_space(1))) void*)g,
        (__attribute__((address_space(3))) void*)l, 16, 0, 0);
}

// ---------------------------------------------------------------------------
// f32 -> bf16 for the three inputs in one launch (memory-bound, float4 vec)
// ---------------------------------------------------------------------------
__global__ __launch_bounds__(256)
void cvt3_kernel(const float* __restrict__ s0, unsigned short* __restrict__ d0, int n0,
                 const float* __restrict__ s1, unsigned short* __restrict__ d1, int n1,
                 const float* __restrict__ s2, unsigned short* __restrict__ d2, int n2)
{
    int i = blockIdx.x * 256 + threadIdx.x;
    const float* s; unsigned short* d; int k;
    if (i < n0)                { s = s0; d = d0; k = i; }
    else if (i < n0 + n1)      { s = s1; d = d1; k = i - n0; }
    else if (i < n0 + n1 + n2) { s = s2; d = d2; k = i - n0 - n1; }
    else return;
    f32x4 v = ((const f32x4*)s)[k];
    bf16x4 o;
#pragma unroll
    for (int e = 0; e < 4; ++e) o[e] = (short)f2bf(v[e]);
    ((bf16x4*)d)[k] = o;
}

// ---------------------------------------------------------------------------
// bf16 MFMA GEMM (BT layout): C[MxN] = A[MxK=512] * Bw[NxK]^T + bias
// 128x128 tile, BK=64, 256 threads (4 waves 2x2), 16x16x32 MFMA.
// - Staging: global_load_lds width=16, LINEAR LDS dest (wave-uniform base +
//   lane*16), with the 16B-chunk GLOBAL SOURCE pre-swizzled by lc = pc^(row&7)
//   (rule #21: linear dest + inverse-swz source + swz read). Read applies the
//   same XOR -> conflict-free ds_read_b128 (round-0 measured 0 conflicts).
// - Double-buffered 2-phase loop: issue next-tile STAGE before computing the
//   current tile; ONE __syncthreads (vmcnt0+lgkmcnt0 drain) per K-step.
// - XCD-aware bijective block swizzle (nwg % 8 == 0 at both call sites).
// MODE 0: bf16 store.  MODE 1: f32 store.
// ---------------------------------------------------------------------------
template<int MODE>
__global__ __launch_bounds__(256)
void gemm_bt(const unsigned short* __restrict__ A, const unsigned short* __restrict__ Bw,
             const float* __restrict__ bias, void* __restrict__ Cout, int ldc, int ntx)
{
    __shared__ unsigned short As[2][128 * 64];   // 32 KiB
    __shared__ unsigned short Bs[2][128 * 64];   // 32 KiB  (64 KiB total)

    const int t = threadIdx.x;
    const int nwg = gridDim.x;
    const int cpx = nwg >> 3;
    const int lin = blockIdx.x;
    const int swz = (lin & 7) * cpx + (lin >> 3);
    const int bx = swz % ntx, by = swz / ntx;
    const int mbase = by * 128, nbase = bx * 128;

    const int w = t >> 6, l = t & 63;
    const int wr = w >> 1, wc = w & 1;
    const int lg = l >> 4, lr = l & 15;

    // staging geometry: physical chunk p = i*256 + t holds global logical
    // chunk lc = (p&7) ^ (row&7) of row = p>>3.
    int soff[4];
#pragma unroll
    for (int i = 0; i < 4; ++i) {
        int p = i * 256 + t;
        int row = p >> 3, pc = p & 7;
        int lc = pc ^ (row & 7);
        soff[i] = row * 512 + lc * 8;            // element offset within panel
    }
    const unsigned short* Ab = A  + (size_t)mbase * 512;
    const unsigned short* Bb = Bw + (size_t)nbase * 512;

    f32x4 acc[4][4] = {};

    auto STAGE = [&](int buf, int ks) {
#pragma unroll
        for (int i = 0; i < 4; ++i) {
            gload_lds16(Ab + soff[i] + ks, &As[buf][(i * 256 + w * 64) * 8]);
            gload_lds16(Bb + soff[i] + ks, &Bs[buf][(i * 256 + w * 64) * 8]);
        }
    };
    auto COMPUTE = [&](int buf) {
#pragma unroll
        for (int kk = 0; kk < 64; kk += 32) {
            const int lc = (kk >> 3) + lg;       // logical 16B chunk index
            bf16x8 af[4], bfr[4];
#pragma unroll
            for (int mi = 0; mi < 4; ++mi) {
                int r = wr * 64 + mi * 16 + lr;
                af[mi] = *(const bf16x8*)&As[buf][r * 64 + ((lc ^ (r & 7)) << 3)];
            }
#pragma unroll
            for (int ni = 0; ni < 4; ++ni) {
                int n = wc * 64 + ni * 16 + lr;
                bfr[ni] = *(const bf16x8*)&Bs[buf][n * 64 + ((lc ^ (n & 7)) << 3)];
            }
#pragma unroll
            for (int mi = 0; mi < 4; ++mi)
#pragma unroll
                for (int ni = 0; ni < 4; ++ni)
                    acc[mi][ni] = __builtin_amdgcn_mfma_f32_16x16x32_bf16(
                        af[mi], bfr[ni], acc[mi][ni], 0, 0, 0);
        }
    };

    // ---- 2-phase double-buffered main loop over 8 K-tiles ----
    int cur = 0;
    STAGE(0, 0);
    __syncthreads();                              // buf0 ready
#pragma unroll 1
    for (int ti = 0; ti < 7; ++ti) {
        STAGE(cur ^ 1, (ti + 1) << 6);            // prefetch next tile
        COMPUTE(cur);                             // overlap with loads in flight
        __syncthreads();                          // drain vmcnt(0): next buf ready
        cur ^= 1;
    }
    COMPUTE(cur);                                 // last tile, no prefetch

    // ---- epilogue: C/D layout col=lane&15, row=(lane>>4)*4+reg ----
#pragma unroll
    for (int ni = 0; ni < 4; ++ni) {
        int col = nbase + wc * 64 + ni * 16 + lr;
        float bv = bias[col];
#pragma unroll
        for (int mi = 0; mi < 4; ++mi) {
            int row0 = mbase + wr * 64 + mi * 16 + lg * 4;
#pragma unroll
            for (int ri = 0; ri < 4; ++ri) {
                float v = acc[mi][ni][ri] + bv;
                if (MODE == 0)
                    ((unsigned short*)Cout)[(size_t)(row0 + ri) * ldc + col] = f2bf(v);
                else
                    ((float*)Cout)[(size_t)(row0 + ri) * ldc + col] = v;
            }
        }
    }
}

// ---------------------------------------------------------------------------
// Attention: one block per (b,h). qkv bf16 in, ctx bf16 out.
// f32 LDS tiles with chunk-XOR swizzle (conflict-free on both access axes).
// Softmax: 8 lanes own one q-row (4 cols each), __shfl_xor reduce.
// ---------------------------------------------------------------------------
__global__ __launch_bounds__(256)
void attn_kernel(const unsigned short* __restrict__ qkv,
                 const unsigned char* __restrict__ pad,
                 unsigned short* __restrict__ ctx)
{
    __shared__ f32x4 Qs[32 * 32];
    __shared__ f32x4 Ks[32 * 32];
    __shared__ f32x4 Vs[32 * 32];
    __shared__ float Ps[32 * 33];

    const int bid = blockIdx.x;
    const int b = bid >> 2, h = bid & 3;
    const int t = threadIdx.x;
    const int r = t >> 3, j = t & 7;     // staging: row r, 16-elem slice j

    // ---- stage Q,K,V (bf16 -> f32, swizzled chunks) ----
    const unsigned short* base = qkv + ((size_t)(b * 32 + r) * 1536 + h * 128);
#pragma unroll
    for (int sel = 0; sel < 3; ++sel) {
        f32x4* dst = (sel == 0) ? Qs : (sel == 1) ? Ks : Vs;
        const unsigned short* src = base + sel * 512 + j * 16;
#pragma unroll
        for (int it = 0; it < 2; ++it) {
            i32x4 raw = *(const i32x4*)(src + it * 8);
            float fv[8];
#pragma unroll
            for (int e = 0; e < 8; ++e) {
                unsigned word = ((const unsigned*)&raw)[e >> 1];
                unsigned short hb = (e & 1) ? (unsigned short)(word >> 16)
                                            : (unsigned short)(word & 0xffffu);
                fv[e] = bf2f(hb);
            }
            int c0 = j * 4 + it * 2;
            f32x4 v0 = {fv[0], fv[1], fv[2], fv[3]};
            f32x4 v1 = {fv[4], fv[5], fv[6], fv[7]};
            dst[r * 32 + ((c0    ) ^ r)] = v0;
            dst[r * 32 + ((c0 + 1) ^ r)] = v1;
        }
    }
    __syncthreads();

    // ---- scores: thread (q = r, cols kc..kc+3), dot over 128 ----
    const int q  = r;
    const int kc = j * 4;
    float s[4] = {0.f, 0.f, 0.f, 0.f};
#pragma unroll 4
    for (int d4 = 0; d4 < 32; ++d4) {
        f32x4 qv = Qs[q * 32 + (d4 ^ q)];
#pragma unroll
        for (int jj = 0; jj < 4; ++jj) {
            f32x4 kv = Ks[(kc + jj) * 32 + (d4 ^ (kc + jj))];
#pragma unroll
            for (int e = 0; e < 4; ++e) s[jj] = fmaf(qv[e], kv[e], s[jj]);
        }
    }
    const float sc = 0.08838834764831845f;   // 1/sqrt(128)
    float m = -INFINITY;
#pragma unroll
    for (int jj = 0; jj < 4; ++jj) {
        int kcol = kc + jj;
        bool msk = (kcol == q) || (pad[b * 32 + kcol] != 0);
        s[jj] = msk ? -INFINITY : s[jj] * sc;
        m = fmaxf(m, s[jj]);
    }
    m = fmaxf(m, __shfl_xor(m, 1));
    m = fmaxf(m, __shfl_xor(m, 2));
    m = fmaxf(m, __shfl_xor(m, 4));
    float p[4], sum = 0.f;
#pragma unroll
    for (int jj = 0; jj < 4; ++jj) { p[jj] = __expf(s[jj] - m); sum += p[jj]; }
    sum += __shfl_xor(sum, 1);
    sum += __shfl_xor(sum, 2);
    sum += __shfl_xor(sum, 4);
#pragma unroll
    for (int jj = 0; jj < 4; ++jj) Ps[q * 33 + kc + jj] = p[jj];
    __syncthreads();

    // ---- PV: thread (q, d-chunks {j, j+8, j+16, j+24}) ----
    float c[16] = {0.f};
#pragma unroll 4
    for (int k = 0; k < 32; ++k) {
        float pv = Ps[q * 33 + k];
#pragma unroll
        for (int cc = 0; cc < 4; ++cc) {
            f32x4 vv = Vs[k * 32 + ((j + 8 * cc) ^ k)];
#pragma unroll
            for (int e = 0; e < 4; ++e) c[cc * 4 + e] = fmaf(pv, vv[e], c[cc * 4 + e]);
        }
    }
    const float inv = 1.0f / sum;
    unsigned short* co = ctx + (size_t)(b * 32 + q) * 512 + h * 128;
#pragma unroll
    for (int cc = 0; cc < 4; ++cc) {
        bf16x4 ov;
#pragma unroll
        for (int e = 0; e < 4; ++e) ov[e] = (short)f2bf(c[cc * 4 + e] * inv);
        *(bf16x4*)(co + (j + 8 * cc) * 4) = ov;
    }
}

// ---------------------------------------------------------------------------
extern "C" void kernel_launch(void* const* d_in, const int* in_sizes, int n_in,
                              void* d_out, int out_size, void* d_ws, size_t ws_size,
                              hipStream_t stream)
{
    const float*         X    = (const float*)d_in[0];
    const unsigned char* pad  = (const unsigned char*)d_in[1];
    const float*         Win  = (const float*)d_in[2];          // (1536, 512)
    const float*         bin  = (const float*)d_in[3];          // (1536,)
    const float*         Wout = (const float*)d_in[4];          // (512, 512)
    const float*         bout = (const float*)d_in[5];          // (512,)
    float*               out  = (float*)d_out;                  // (1024,32,512) f32

    // workspace plan (~130.2 MiB):
    //   [0, 96MiB)        qkvb  bf16 32768x1536
    //   [96MiB, 128MiB)   Xb    bf16 32768x512 (dead after qkv) / ctxb aliases
    //   [128MiB, ...)     Winb  bf16 1536x512, Woutb bf16 512x512
    char* ws = (char*)d_ws;
    unsigned short* qkvb  = (unsigned short*)(ws);
    unsigned short* Xb    = (unsigned short*)(ws + (size_t)100663296);
    unsigned short* ctxb  = Xb;
    unsigned short* Winb  = (unsigned short*)(ws + (size_t)134217728);
    unsigned short* Woutb = (unsigned short*)(ws + (size_t)135790592);

    dim3 blk(256);
    // f32 -> bf16 conversions: 4194304 + 196608 + 65536 f4-chunks = 17408 blocks
    cvt3_kernel<<<dim3(17408), blk, 0, stream>>>(X, Xb, 4194304,
                                                 Win, Winb, 196608,
                                                 Wout, Woutb, 65536);
    // qkv projection: 256 M-tiles x 12 N-tiles = 3072 blocks
    gemm_bt<0><<<dim3(3072), blk, 0, stream>>>(Xb, Winb, bin, qkvb, 1536, 12);
    // attention: 1024 batches x 4 heads
    attn_kernel<<<dim3(4096), blk, 0, stream>>>(qkvb, pad, ctxb);
    // output projection: 256 M-tiles x 4 N-tiles = 1024 blocks
    gemm_bt<1><<<dim3(1024), blk, 0, stream>>>(ctxb, Woutb, bout, out, 512, 4);
}

// Round 5
// 257.674 us; speedup vs baseline: 1.4413x; 1.1214x over previous
//
#include <hip/hip_runtime.h>
#include <hip/hip_bf16.h>

// Problem: B=1024, N=32, D=512, H=4, HD=128
// Pipeline:
//   cvt3:  X, Win, Wout f32 -> bf16 (one launch)
//   qk   = Xb(32768x512) @ WinQK^T + bQK        -> bf16 qkb[32768][1024]
//   Vt   = WinV(512x512) @ Xb^T  (+bV by row)   -> bf16 Vtb[512][32768]
//   attn: per-(b,h) WAVE, MFMA 32x32x16, no LDS -> bf16 ctxb
//   out  = ctxb @ Woutb^T + bout                -> f32 d_out

typedef __attribute__((ext_vector_type(4)))  float f32x4;
typedef __attribute__((ext_vector_type(16))) float f32x16;
typedef __attribute__((ext_vector_type(8)))  short bf16x8;
typedef __attribute__((ext_vector_type(4)))  short bf16x4;
typedef __attribute__((ext_vector_type(4)))  int   i32x4;

__device__ __forceinline__ unsigned short f2bf(float f) {
    unsigned u = __builtin_bit_cast(unsigned, f);
    u = (u + 0x7FFFu + ((u >> 16) & 1u)) >> 16;   // RNE
    return (unsigned short)u;
}

__device__ __forceinline__ void gload_lds16(const void* g, void* l) {
    __builtin_amdgcn_global_load_lds(
        (const __attribute__((address_space(1))) void*)g,
        (__attribute__((address_space(3))) void*)l, 16, 0, 0);
}

// ---------------------------------------------------------------------------
// f32 -> bf16 for the three inputs in one launch
// ---------------------------------------------------------------------------
__global__ __launch_bounds__(256)
void cvt3_kernel(const float* __restrict__ s0, unsigned short* __restrict__ d0, int n0,
                 const float* __restrict__ s1, unsigned short* __restrict__ d1, int n1,
                 const float* __restrict__ s2, unsigned short* __restrict__ d2, int n2)
{
    int i = blockIdx.x * 256 + threadIdx.x;
    const float* s; unsigned short* d; int k;
    if (i < n0)                { s = s0; d = d0; k = i; }
    else if (i < n0 + n1)      { s = s1; d = d1; k = i - n0; }
    else if (i < n0 + n1 + n2) { s = s2; d = d2; k = i - n0 - n1; }
    else return;
    f32x4 v = ((const f32x4*)s)[k];
    bf16x4 o;
#pragma unroll
    for (int e = 0; e < 4; ++e) o[e] = (short)f2bf(v[e]);
    ((bf16x4*)d)[k] = o;
}

// ---------------------------------------------------------------------------
// bf16 MFMA GEMM (BT layout): C[MxN] = A[MxK=512] * Bw[NxK]^T + bias
// 128x128 tile, BK=64, 256 threads (4 waves 2x2), 16x16x32 MFMA.
// Double-buffered 2-phase loop; global_load_lds w16 with source-side chunk
// XOR pre-swizzle + matching read XOR (rule #21); XCD-bijective block swizzle.
// MODE 0: bf16 store, bias[col].  MODE 1: f32 store, bias[col].
// MODE 2: bf16 store, bias[row]   (used for the Vt = WinV * X^T GEMM).
// ---------------------------------------------------------------------------
template<int MODE>
__global__ __launch_bounds__(256)
void gemm_bt(const unsigned short* __restrict__ A, const unsigned short* __restrict__ Bw,
             const float* __restrict__ bias, void* __restrict__ Cout, int ldc, int ntx)
{
    __shared__ unsigned short As[2][128 * 64];
    __shared__ unsigned short Bs[2][128 * 64];

    const int t = threadIdx.x;
    const int nwg = gridDim.x;
    const int cpx = nwg >> 3;
    const int lin = blockIdx.x;
    const int swz = (lin & 7) * cpx + (lin >> 3);
    const int bx = swz % ntx, by = swz / ntx;
    const int mbase = by * 128, nbase = bx * 128;

    const int w = t >> 6, l = t & 63;
    const int wr = w >> 1, wc = w & 1;
    const int lg = l >> 4, lr = l & 15;

    // physical chunk p = i*256+t holds logical chunk (p&7)^(row&7) of row p>>3
    int soff[4];
#pragma unroll
    for (int i = 0; i < 4; ++i) {
        int p = i * 256 + t;
        int row = p >> 3, pc = p & 7;
        soff[i] = row * 512 + (pc ^ (row & 7)) * 8;
    }
    const unsigned short* Ab = A  + (size_t)mbase * 512;
    const unsigned short* Bb = Bw + (size_t)nbase * 512;

    f32x4 acc[4][4] = {};

    auto STAGE = [&](int buf, int ks) {
#pragma unroll
        for (int i = 0; i < 4; ++i) {
            gload_lds16(Ab + soff[i] + ks, &As[buf][(i * 256 + w * 64) * 8]);
            gload_lds16(Bb + soff[i] + ks, &Bs[buf][(i * 256 + w * 64) * 8]);
        }
    };
    auto COMPUTE = [&](int buf) {
#pragma unroll
        for (int kk = 0; kk < 64; kk += 32) {
            const int lc = (kk >> 3) + lg;
            bf16x8 af[4], bfr[4];
#pragma unroll
            for (int mi = 0; mi < 4; ++mi) {
                int r = wr * 64 + mi * 16 + lr;
                af[mi] = *(const bf16x8*)&As[buf][r * 64 + ((lc ^ (r & 7)) << 3)];
            }
#pragma unroll
            for (int ni = 0; ni < 4; ++ni) {
                int n = wc * 64 + ni * 16 + lr;
                bfr[ni] = *(const bf16x8*)&Bs[buf][n * 64 + ((lc ^ (n & 7)) << 3)];
            }
#pragma unroll
            for (int mi = 0; mi < 4; ++mi)
#pragma unroll
                for (int ni = 0; ni < 4; ++ni)
                    acc[mi][ni] = __builtin_amdgcn_mfma_f32_16x16x32_bf16(
                        af[mi], bfr[ni], acc[mi][ni], 0, 0, 0);
        }
    };

    int cur = 0;
    STAGE(0, 0);
    __syncthreads();
#pragma unroll 1
    for (int ti = 0; ti < 7; ++ti) {
        STAGE(cur ^ 1, (ti + 1) << 6);
        COMPUTE(cur);
        __syncthreads();
        cur ^= 1;
    }
    COMPUTE(cur);

    // epilogue: C/D col=lane&15, row=(lane>>4)*4+reg
    float brow[4][4];
    if (MODE == 2) {
#pragma unroll
        for (int mi = 0; mi < 4; ++mi)
#pragma unroll
            for (int ri = 0; ri < 4; ++ri)
                brow[mi][ri] = bias[mbase + wr * 64 + mi * 16 + lg * 4 + ri];
    }
#pragma unroll
    for (int ni = 0; ni < 4; ++ni) {
        int col = nbase + wc * 64 + ni * 16 + lr;
        float bcol = (MODE == 2) ? 0.f : bias[col];
#pragma unroll
        for (int mi = 0; mi < 4; ++mi) {
            int row0 = mbase + wr * 64 + mi * 16 + lg * 4;
#pragma unroll
            for (int ri = 0; ri < 4; ++ri) {
                float v = acc[mi][ni][ri] + ((MODE == 2) ? brow[mi][ri] : bcol);
                if (MODE == 1)
                    ((float*)Cout)[(size_t)(row0 + ri) * ldc + col] = v;
                else
                    ((unsigned short*)Cout)[(size_t)(row0 + ri) * ldc + col] = f2bf(v);
            }
        }
    }
}

// ---------------------------------------------------------------------------
// MFMA attention: ONE WAVE per (b,h). No LDS, no block sync.
// S' = K Q^T via mfma_32x32x16 (swapped: lane holds col q = l&31, 16 k-rows)
// in-register masked softmax; P is NORMALIZED IN-REGISTER (each lane's p[]
// all belong to query q=l&31, so p*=inv is exact row normalization) BEFORE
// the bf16 pack — the PV output then needs no per-row scaling (the round-4
// bug: applying inv after PV normalized row qr by row q's denominator).
// ctx = P V via mfma with B-frags read contiguously from Vt[512][32768].
// A/B frag: lane l -> row/col l&31, k = (l>>5)*8..+7.  C/D: col=lane&31,
// row = (reg&3)+8*(reg>>2)+4*(lane>>5).
// ---------------------------------------------------------------------------
__global__ __launch_bounds__(256)
void attn_mfma(const unsigned short* __restrict__ qk,
               const unsigned short* __restrict__ Vt,
               const unsigned char* __restrict__ pad,
               unsigned short* __restrict__ ctx)
{
    const int wid = blockIdx.x * 4 + (threadIdx.x >> 6);   // 4096 waves
    const int b = wid >> 2, h = wid & 3;
    const int l = threadIdx.x & 63;
    const int q = l & 31;           // this lane's column (query index)
    const int hi = l >> 5;

    const unsigned short* rowp = qk + (size_t)(b * 32 + q) * 1024 + h * 128;

    // ---- S' = K Q^T over d=128 (8 mfma) ----
    f32x16 s = {};
#pragma unroll
    for (int st = 0; st < 8; ++st) {
        int d0 = st * 16 + hi * 8;
        bf16x8 kf = *(const bf16x8*)(rowp + 512 + d0);   // K[agent=q-lane][d0..+7]
        bf16x8 qf = *(const bf16x8*)(rowp + d0);         // Q[agent=q-lane][d0..+7]
        s = __builtin_amdgcn_mfma_f32_32x32x16_bf16(kf, qf, s, 0, 0, 0);
    }

    // ---- masked softmax along k (rows of S' = regs + partner lane) ----
    unsigned long long bal = __ballot(pad[b * 32 + q] != 0);
    unsigned padbits = (unsigned)bal | (unsigned)(bal >> 32);
    const float sc = 0.08838834764831845f;   // 1/sqrt(128)
    float sv[16];
    float m = -INFINITY;
#pragma unroll
    for (int r = 0; r < 16; ++r) {
        int k = (r & 3) + 8 * (r >> 2) + 4 * hi;
        bool msk = (k == q) || ((padbits >> k) & 1u);
        sv[r] = msk ? -INFINITY : s[r] * sc;
        m = fmaxf(m, sv[r]);
    }
    m = fmaxf(m, __shfl_xor(m, 32));
    float p[16], sum = 0.f;
#pragma unroll
    for (int r = 0; r < 16; ++r) { p[r] = __expf(sv[r] - m); sum += p[r]; }
    sum += __shfl_xor(sum, 32);
    const float inv = 1.0f / sum;
    // normalize row q HERE (all p[r] of this lane belong to query q)
#pragma unroll
    for (int r = 0; r < 16; ++r) p[r] *= inv;

    // ---- pack normalized P -> bf16 A-fragments (two k-windows of 16) ----
    bf16x8 pa[2];
#pragma unroll
    for (int t2 = 0; t2 < 2; ++t2) {
        unsigned pk[4], pw[4];
#pragma unroll
        for (int i = 0; i < 4; ++i)
            pk[i] = ((unsigned)f2bf(p[8 * t2 + 2 * i + 1]) << 16)
                  |  (unsigned)f2bf(p[8 * t2 + 2 * i]);
#pragma unroll
        for (int i = 0; i < 4; ++i)
            pw[i] = (unsigned)__shfl_xor((int)pk[i], 32);
        unsigned w0 = hi ? pw[2] : pk[0];
        unsigned w1 = hi ? pw[3] : pk[1];
        unsigned w2 = hi ? pk[2] : pw[0];
        unsigned w3 = hi ? pk[3] : pw[1];
        i32x4 wv = {(int)w0, (int)w1, (int)w2, (int)w3};
        pa[t2] = __builtin_bit_cast(bf16x8, wv);
    }

    // ---- ctx = P V : 4 d-tiles x 2 k-steps; B-frags contiguous from Vt ----
#pragma unroll
    for (int dt = 0; dt < 4; ++dt) {
        f32x16 c = {};
#pragma unroll
        for (int t2 = 0; t2 < 2; ++t2) {
            const unsigned short* vp =
                Vt + (size_t)(h * 128 + dt * 32 + q) * 32768 + b * 32 + t2 * 16 + hi * 8;
            bf16x8 vb = *(const bf16x8*)vp;
            c = __builtin_amdgcn_mfma_f32_32x32x16_bf16(pa[t2], vb, c, 0, 0, 0);
        }
        // write: col = lane&31 = d-within-tile, row = query qr (P pre-normalized)
        unsigned short* co = ctx + (size_t)(b * 32) * 512 + h * 128 + dt * 32 + q;
#pragma unroll
        for (int r = 0; r < 16; ++r) {
            int qr = (r & 3) + 8 * (r >> 2) + 4 * hi;
            co[(size_t)qr * 512] = f2bf(c[r]);
        }
    }
}

// ---------------------------------------------------------------------------
extern "C" void kernel_launch(void* const* d_in, const int* in_sizes, int n_in,
                              void* d_out, int out_size, void* d_ws, size_t ws_size,
                              hipStream_t stream)
{
    const float*         X    = (const float*)d_in[0];
    const unsigned char* pad  = (const unsigned char*)d_in[1];
    const float*         Win  = (const float*)d_in[2];          // (1536, 512)
    const float*         bin  = (const float*)d_in[3];          // (1536,)
    const float*         Wout = (const float*)d_in[4];          // (512, 512)
    const float*         bout = (const float*)d_in[5];          // (512,)
    float*               out  = (float*)d_out;                  // (1024,32,512) f32

    // workspace (~130.2 MiB):
    //   [0, 64MiB)          qkb   bf16 32768x1024  (Q cols 0..511, K 512..1023)
    //   [64MiB, 96MiB)      Vtb   bf16 512x32768   ([h][d][b][k] transposed V)
    //   [96MiB, 128MiB)     Xb    bf16 32768x512 (dead after GEMMs) / ctxb alias
    //   [128MiB, ...)       Winb bf16 1536x512, Woutb bf16 512x512
    char* ws = (char*)d_ws;
    unsigned short* qkb   = (unsigned short*)(ws);
    unsigned short* Vtb   = (unsigned short*)(ws + (size_t)67108864);
    unsigned short* Xb    = (unsigned short*)(ws + (size_t)100663296);
    unsigned short* ctxb  = Xb;
    unsigned short* Winb  = (unsigned short*)(ws + (size_t)134217728);
    unsigned short* Woutb = (unsigned short*)(ws + (size_t)135790592);

    dim3 blk(256);
    cvt3_kernel<<<dim3(17408), blk, 0, stream>>>(X, Xb, 4194304,
                                                 Win, Winb, 196608,
                                                 Wout, Woutb, 65536);
    // QK projection: rows 0..1023 of Win; 256 M-tiles x 8 N-tiles
    gemm_bt<0><<<dim3(2048), blk, 0, stream>>>(Xb, Winb, bin, qkb, 1024, 8);
    // V^T projection: Vt[v][row] = WinV . Xb^T; 4 M-tiles x 256 N-tiles
    gemm_bt<2><<<dim3(1024), blk, 0, stream>>>(Winb + (size_t)1024 * 512, Xb,
                                               bin + 1024, Vtb, 32768, 256);
    // attention: 4096 (b,h) waves = 1024 blocks x 4 waves
    attn_mfma<<<dim3(1024), blk, 0, stream>>>(qkb, Vtb, pad, ctxb);
    // output projection: 256 M-tiles x 4 N-tiles
    gemm_bt<1><<<dim3(1024), blk, 0, stream>>>(ctxb, Woutb, bout, out, 512, 4);
}

// Round 8
// 252.579 us; speedup vs baseline: 1.4704x; 1.0202x over previous
//
#include <hip/hip_runtime.h>
#include <hip/hip_bf16.h>

// Problem: B=1024, N=32, D=512, H=4, HD=128
// Pipeline:
//   cvt3:  X, Win, Wout f32 -> bf16 (one launch)
//   qkvt (fused, 3072 blocks):
//     blocks 0..2047:  qk = Xb @ WinQK^T + bQK  -> qkb2[b][h][sel][agent][128]
//     blocks 2048..:   Vt = WinV @ Xb^T + bV    -> vtb2[b][h][d][agent]
//   attn: per-(b,h) WAVE, MFMA 32x32x16, no LDS; reads compact 8KB tiles
//   out  = ctxb @ Woutb^T + bout                -> f32 d_out

typedef __attribute__((ext_vector_type(4)))  float f32x4;
typedef __attribute__((ext_vector_type(16))) float f32x16;
typedef __attribute__((ext_vector_type(8)))  short bf16x8;
typedef __attribute__((ext_vector_type(4)))  short bf16x4;
typedef __attribute__((ext_vector_type(4)))  int   i32x4;

__device__ __forceinline__ unsigned short f2bf(float f) {
    unsigned u = __builtin_bit_cast(unsigned, f);
    u = (u + 0x7FFFu + ((u >> 16) & 1u)) >> 16;   // RNE
    return (unsigned short)u;
}

__device__ __forceinline__ void gload_lds16(const void* g, void* l) {
    __builtin_amdgcn_global_load_lds(
        (const __attribute__((address_space(1))) void*)g,
        (__attribute__((address_space(3))) void*)l, 16, 0, 0);
}

// ---------------------------------------------------------------------------
// f32 -> bf16 for the three inputs in one launch
// ---------------------------------------------------------------------------
__global__ __launch_bounds__(256)
void cvt3_kernel(const float* __restrict__ s0, unsigned short* __restrict__ d0, int n0,
                 const float* __restrict__ s1, unsigned short* __restrict__ d1, int n1,
                 const float* __restrict__ s2, unsigned short* __restrict__ d2, int n2)
{
    int i = blockIdx.x * 256 + threadIdx.x;
    const float* s; unsigned short* d; int k;
    if (i < n0)                { s = s0; d = d0; k = i; }
    else if (i < n0 + n1)      { s = s1; d = d1; k = i - n0; }
    else if (i < n0 + n1 + n2) { s = s2; d = d2; k = i - n0 - n1; }
    else return;
    f32x4 v = ((const f32x4*)s)[k];
    bf16x4 o;
#pragma unroll
    for (int e = 0; e < 4; ++e) o[e] = (short)f2bf(v[e]);
    ((bf16x4*)d)[k] = o;
}

// ---------------------------------------------------------------------------
// Fused projection GEMM (both are BT-layout bf16 MFMA, 128x128 tile, BK=64,
// 256 thr / 4 waves, dbuf 2-phase, gload_lds w16 + source-side chunk XOR
// pre-swizzle + matching read XOR, per-segment XCD-bijective swizzle):
//   blocks [0,2048):   C = Xb(32768x512) @ Winb[0:1024]^T + bin[col]
//                      scattered-store to qkb2[b][h][sel][agent][d]
//   blocks [2048,3072): C = WinV(512x512) @ Xb^T + bin[1024+row]
//                      scattered-store to vtb2[b][h][d][agent]
// Both remapped stores keep 16-lane x 2B = 32B contiguous runs (same
// coalescing as plain row-major).
// ---------------------------------------------------------------------------
__global__ __launch_bounds__(256)
void gemm_qkvt(const unsigned short* __restrict__ Xb,
               const unsigned short* __restrict__ Winb,
               const float* __restrict__ bin,
               unsigned short* __restrict__ qkb2,
               unsigned short* __restrict__ vtb2)
{
    __shared__ unsigned short As[2][128 * 64];
    __shared__ unsigned short Bs[2][128 * 64];

    const int t = threadIdx.x;
    const int lin = blockIdx.x;
    const bool isVt = lin >= 2048;
    int mbase, nbase;
    const unsigned short *Ap, *Bp;
    if (!isVt) {
        int swz = (lin & 7) * 256 + (lin >> 3);        // nwg=2048, cpx=256
        nbase = (swz & 7) * 128;                       // 8 N-tiles
        mbase = (swz >> 3) * 128;                      // 256 M-tiles
        Ap = Xb; Bp = Winb;
    } else {
        int l2 = lin - 2048;
        int swz = (l2 & 7) * 128 + (l2 >> 3);          // nwg=1024, cpx=128
        nbase = (swz & 255) * 128;                     // 256 N-tiles
        mbase = (swz >> 8) * 128;                      // 4 M-tiles
        Ap = Winb + (size_t)1024 * 512; Bp = Xb;
    }

    const int w = t >> 6, l = t & 63;
    const int wr = w >> 1, wc = w & 1;
    const int lg = l >> 4, lr = l & 15;

    // physical chunk p = i*256+t holds logical chunk (p&7)^(row&7) of row p>>3
    int soff[4];
#pragma unroll
    for (int i = 0; i < 4; ++i) {
        int p = i * 256 + t;
        int row = p >> 3, pc = p & 7;
        soff[i] = row * 512 + (pc ^ (row & 7)) * 8;
    }
    const unsigned short* Ab = Ap + (size_t)mbase * 512;
    const unsigned short* Bb = Bp + (size_t)nbase * 512;

    f32x4 acc[4][4] = {};

    auto STAGE = [&](int buf, int ks) {
#pragma unroll
        for (int i = 0; i < 4; ++i) {
            gload_lds16(Ab + soff[i] + ks, &As[buf][(i * 256 + w * 64) * 8]);
            gload_lds16(Bb + soff[i] + ks, &Bs[buf][(i * 256 + w * 64) * 8]);
        }
    };
    auto COMPUTE = [&](int buf) {
#pragma unroll
        for (int kk = 0; kk < 64; kk += 32) {
            const int lc = (kk >> 3) + lg;
            bf16x8 af[4], bfr[4];
#pragma unroll
            for (int mi = 0; mi < 4; ++mi) {
                int r = wr * 64 + mi * 16 + lr;
                af[mi] = *(const bf16x8*)&As[buf][r * 64 + ((lc ^ (r & 7)) << 3)];
            }
#pragma unroll
            for (int ni = 0; ni < 4; ++ni) {
                int n = wc * 64 + ni * 16 + lr;
                bfr[ni] = *(const bf16x8*)&Bs[buf][n * 64 + ((lc ^ (n & 7)) << 3)];
            }
#pragma unroll
            for (int mi = 0; mi < 4; ++mi)
#pragma unroll
                for (int ni = 0; ni < 4; ++ni)
                    acc[mi][ni] = __builtin_amdgcn_mfma_f32_16x16x32_bf16(
                        af[mi], bfr[ni], acc[mi][ni], 0, 0, 0);
        }
    };

    int cur = 0;
    STAGE(0, 0);
    __syncthreads();
#pragma unroll 1
    for (int ti = 0; ti < 7; ++ti) {
        STAGE(cur ^ 1, (ti + 1) << 6);
        COMPUTE(cur);
        __syncthreads();
        cur ^= 1;
    }
    COMPUTE(cur);

    // ---- epilogue: C/D col=lane&15, row=(lane>>4)*4+reg; remapped stores ----
    if (!isVt) {
#pragma unroll
        for (int ni = 0; ni < 4; ++ni) {
            int col = nbase + wc * 64 + ni * 16 + lr;     // 0..1023
            float bcol = bin[col];
            int sel = col >> 9;                            // 0=Q, 1=K
            int h   = (col >> 7) & 3;
            int d   = col & 127;
            unsigned short* ob = qkb2 + (size_t)h * 8192 + (size_t)sel * 4096 + d;
#pragma unroll
            for (int mi = 0; mi < 4; ++mi) {
                int row0 = mbase + wr * 64 + mi * 16 + lg * 4;
#pragma unroll
                for (int ri = 0; ri < 4; ++ri) {
                    int row = row0 + ri;
                    int bb = row >> 5, ag = row & 31;
                    ob[(size_t)bb * 32768 + ag * 128] = f2bf(acc[mi][ni][ri] + bcol);
                }
            }
        }
    } else {
#pragma unroll
        for (int ni = 0; ni < 4; ++ni) {
            int col = nbase + wc * 64 + ni * 16 + lr;     // 0..32767 = b*32+ag
            int bb = col >> 5, ag = col & 31;
            unsigned short* ob = vtb2 + (size_t)bb * 16384 + ag;
#pragma unroll
            for (int mi = 0; mi < 4; ++mi) {
                int row0 = mbase + wr * 64 + mi * 16 + lg * 4;
#pragma unroll
                for (int ri = 0; ri < 4; ++ri) {
                    int row = row0 + ri;                   // v = h*128+d
                    float v = acc[mi][ni][ri] + bin[1024 + row];
                    int h = row >> 7, d = row & 127;
                    ob[(size_t)h * 4096 + d * 32] = f2bf(v);
                }
            }
        }
    }
}

// ---------------------------------------------------------------------------
// bf16 MFMA GEMM for out-proj: C[MxN] = A[MxK=512] * Bw[NxK]^T + bias, f32 out
// (identical structure to round-5 gemm_bt MODE 1)
// ---------------------------------------------------------------------------
__global__ __launch_bounds__(256)
void gemm_out(const unsigned short* __restrict__ A, const unsigned short* __restrict__ Bw,
              const float* __restrict__ bias, float* __restrict__ Cout, int ldc, int ntx)
{
    __shared__ unsigned short As[2][128 * 64];
    __shared__ unsigned short Bs[2][128 * 64];

    const int t = threadIdx.x;
    const int nwg = gridDim.x;
    const int cpx = nwg >> 3;
    const int lin = blockIdx.x;
    const int swz = (lin & 7) * cpx + (lin >> 3);
    const int bx = swz % ntx, by = swz / ntx;
    const int mbase = by * 128, nbase = bx * 128;

    const int w = t >> 6, l = t & 63;
    const int wr = w >> 1, wc = w & 1;
    const int lg = l >> 4, lr = l & 15;

    int soff[4];
#pragma unroll
    for (int i = 0; i < 4; ++i) {
        int p = i * 256 + t;
        int row = p >> 3, pc = p & 7;
        soff[i] = row * 512 + (pc ^ (row & 7)) * 8;
    }
    const unsigned short* Ab = A  + (size_t)mbase * 512;
    const unsigned short* Bb = Bw + (size_t)nbase * 512;

    f32x4 acc[4][4] = {};

    auto STAGE = [&](int buf, int ks) {
#pragma unroll
        for (int i = 0; i < 4; ++i) {
            gload_lds16(Ab + soff[i] + ks, &As[buf][(i * 256 + w * 64) * 8]);
            gload_lds16(Bb + soff[i] + ks, &Bs[buf][(i * 256 + w * 64) * 8]);
        }
    };
    auto COMPUTE = [&](int buf) {
#pragma unroll
        for (int kk = 0; kk < 64; kk += 32) {
            const int lc = (kk >> 3) + lg;
            bf16x8 af[4], bfr[4];
#pragma unroll
            for (int mi = 0; mi < 4; ++mi) {
                int r = wr * 64 + mi * 16 + lr;
                af[mi] = *(const bf16x8*)&As[buf][r * 64 + ((lc ^ (r & 7)) << 3)];
            }
#pragma unroll
            for (int ni = 0; ni < 4; ++ni) {
                int n = wc * 64 + ni * 16 + lr;
                bfr[ni] = *(const bf16x8*)&Bs[buf][n * 64 + ((lc ^ (n & 7)) << 3)];
            }
#pragma unroll
            for (int mi = 0; mi < 4; ++mi)
#pragma unroll
                for (int ni = 0; ni < 4; ++ni)
                    acc[mi][ni] = __builtin_amdgcn_mfma_f32_16x16x32_bf16(
                        af[mi], bfr[ni], acc[mi][ni], 0, 0, 0);
        }
    };

    int cur = 0;
    STAGE(0, 0);
    __syncthreads();
#pragma unroll 1
    for (int ti = 0; ti < 7; ++ti) {
        STAGE(cur ^ 1, (ti + 1) << 6);
        COMPUTE(cur);
        __syncthreads();
        cur ^= 1;
    }
    COMPUTE(cur);

#pragma unroll
    for (int ni = 0; ni < 4; ++ni) {
        int col = nbase + wc * 64 + ni * 16 + lr;
        float bcol = bias[col];
#pragma unroll
        for (int mi = 0; mi < 4; ++mi) {
            int row0 = mbase + wr * 64 + mi * 16 + lg * 4;
#pragma unroll
            for (int ri = 0; ri < 4; ++ri)
                Cout[(size_t)(row0 + ri) * ldc + col] = acc[mi][ni][ri] + bcol;
        }
    }
}

// ---------------------------------------------------------------------------
// MFMA attention: ONE WAVE per (b,h), block = one batch (4 heads). No LDS.
// All reads hit compact per-(b,h) 8KB blocks (L1-resident):
//   qkb2[b][h][sel][agent][128], vtb2[b][h][d][agent].
// S' = K Q^T (swapped: lane col = q = l&31); in-register masked softmax;
// P normalized in-register then packed to bf16 (partner half via shfl_xor);
// ctx = P V. A/B frag: lane -> row/col l&31, k=(l>>5)*8..+7. C/D: col=lane&31,
// row=(reg&3)+8*(reg>>2)+4*(lane>>5).
// ---------------------------------------------------------------------------
__global__ __launch_bounds__(256)
void attn_mfma(const unsigned short* __restrict__ qkb2,
               const unsigned short* __restrict__ vtb2,
               const unsigned char* __restrict__ pad,
               unsigned short* __restrict__ ctx)
{
    const int b = blockIdx.x;
    const int h = threadIdx.x >> 6;
    const int l = threadIdx.x & 63;
    const int q = l & 31;
    const int hi = l >> 5;

    const unsigned short* qb = qkb2 + (size_t)b * 32768 + (size_t)h * 8192;
    const unsigned short* kb = qb + 4096;

    // ---- S' = K Q^T over d=128 (8 mfma) ----
    f32x16 s = {};
#pragma unroll
    for (int st = 0; st < 8; ++st) {
        int d0 = st * 16 + hi * 8;
        bf16x8 kf = *(const bf16x8*)(kb + q * 128 + d0);
        bf16x8 qf = *(const bf16x8*)(qb + q * 128 + d0);
        s = __builtin_amdgcn_mfma_f32_32x32x16_bf16(kf, qf, s, 0, 0, 0);
    }

    // ---- masked softmax along k ----
    unsigned long long bal = __ballot(pad[b * 32 + q] != 0);
    unsigned padbits = (unsigned)bal | (unsigned)(bal >> 32);
    const float sc = 0.08838834764831845f;   // 1/sqrt(128)
    float sv[16];
    float m = -INFINITY;
#pragma unroll
    for (int r = 0; r < 16; ++r) {
        int k = (r & 3) + 8 * (r >> 2) + 4 * hi;
        bool msk = (k == q) || ((padbits >> k) & 1u);
        sv[r] = msk ? -INFINITY : s[r] * sc;
        m = fmaxf(m, sv[r]);
    }
    m = fmaxf(m, __shfl_xor(m, 32));
    float p[16], sum = 0.f;
#pragma unroll
    for (int r = 0; r < 16; ++r) { p[r] = __expf(sv[r] - m); sum += p[r]; }
    sum += __shfl_xor(sum, 32);
    const float inv = 1.0f / sum;
#pragma unroll
    for (int r = 0; r < 16; ++r) p[r] *= inv;   // row-q normalization (lane-local)

    // ---- pack normalized P -> bf16 A-fragments (two k-windows of 16) ----
    bf16x8 pa[2];
#pragma unroll
    for (int t2 = 0; t2 < 2; ++t2) {
        unsigned pk[4], pw[4];
#pragma unroll
        for (int i = 0; i < 4; ++i)
            pk[i] = ((unsigned)f2bf(p[8 * t2 + 2 * i + 1]) << 16)
                  |  (unsigned)f2bf(p[8 * t2 + 2 * i]);
#pragma unroll
        for (int i = 0; i < 4; ++i)
            pw[i] = (unsigned)__shfl_xor((int)pk[i], 32);
        unsigned w0 = hi ? pw[2] : pk[0];
        unsigned w1 = hi ? pw[3] : pk[1];
        unsigned w2 = hi ? pk[2] : pw[0];
        unsigned w3 = hi ? pk[3] : pw[1];
        i32x4 wv = {(int)w0, (int)w1, (int)w2, (int)w3};
        pa[t2] = __builtin_bit_cast(bf16x8, wv);
    }

    // ---- ctx = P V : 4 d-tiles x 2 k-steps; V^T frags 16B-contiguous ----
    const unsigned short* vb_ = vtb2 + (size_t)b * 16384 + (size_t)h * 4096;
#pragma unroll
    for (int dt = 0; dt < 4; ++dt) {
        f32x16 c = {};
#pragma unroll
        for (int t2 = 0; t2 < 2; ++t2) {
            bf16x8 vb = *(const bf16x8*)(vb_ + (dt * 32 + q) * 32 + t2 * 16 + hi * 8);
            c = __builtin_amdgcn_mfma_f32_32x32x16_bf16(pa[t2], vb, c, 0, 0, 0);
        }
        unsigned short* co = ctx + (size_t)(b * 32) * 512 + h * 128 + dt * 32 + q;
#pragma unroll
        for (int r = 0; r < 16; ++r) {
            int qr = (r & 3) + 8 * (r >> 2) + 4 * hi;
            co[(size_t)qr * 512] = f2bf(c[r]);
        }
    }
}

// ---------------------------------------------------------------------------
extern "C" void kernel_launch(void* const* d_in, const int* in_sizes, int n_in,
                              void* d_out, int out_size, void* d_ws, size_t ws_size,
                              hipStream_t stream)
{
    const float*         X    = (const float*)d_in[0];
    const unsigned char* pad  = (const unsigned char*)d_in[1];
    const float*         Win  = (const float*)d_in[2];          // (1536, 512)
    const float*         bin  = (const float*)d_in[3];          // (1536,)
    const float*         Wout = (const float*)d_in[4];          // (512, 512)
    const float*         bout = (const float*)d_in[5];          // (512,)
    float*               out  = (float*)d_out;                  // (1024,32,512) f32

    // workspace (~130.2 MiB):
    //   [0, 64MiB)        qkb2 bf16 [1024][4][2][32][128]
    //   [64MiB, 96MiB)    vtb2 bf16 [1024][4][128][32]
    //   [96MiB, 128MiB)   Xb bf16 32768x512 (dead after proj GEMMs) / ctxb alias
    //   [128MiB, ...)     Winb bf16 1536x512, Woutb bf16 512x512
    char* ws = (char*)d_ws;
    unsigned short* qkb2  = (unsigned short*)(ws);
    unsigned short* vtb2  = (unsigned short*)(ws + (size_t)67108864);
    unsigned short* Xb    = (unsigned short*)(ws + (size_t)100663296);
    unsigned short* ctxb  = Xb;
    unsigned short* Winb  = (unsigned short*)(ws + (size_t)134217728);
    unsigned short* Woutb = (unsigned short*)(ws + (size_t)135790592);

    dim3 blk(256);
    cvt3_kernel<<<dim3(17408), blk, 0, stream>>>(X, Xb, 4194304,
                                                 Win, Winb, 196608,
                                                 Wout, Woutb, 65536);
    // fused projections: 2048 QK blocks + 1024 Vt blocks
    gemm_qkvt<<<dim3(3072), blk, 0, stream>>>(Xb, Winb, bin, qkb2, vtb2);
    // attention: block = batch, 4 head-waves
    attn_mfma<<<dim3(1024), blk, 0, stream>>>(qkb2, vtb2, pad, ctxb);
    // output projection: 256 M-tiles x 4 N-tiles
    gemm_out<<<dim3(1024), blk, 0, stream>>>(ctxb, Woutb, bout, out, 512, 4);
}